// Round 10
// baseline (597.149 us; speedup 1.0000x reference)
//
#include <hip/hip_runtime.h>
#include <hip/hip_bf16.h>
#include <math.h>

// ---- problem constants ----
#define BATCH 4
#define CCH   192
#define HH    56
#define WW    56
#define LSEQ  (HH*WW)          // 3136
#define NTOK  (BATCH*LSEQ)     // 12544
#define DST   16               // D_STATE
#define DIN   384              // D_INNER
#define DTR   12               // DT_RANK
#define NXC   416              // combined x_proj+dt_proj output cols
#define CL    64               // scan chunk length
#define NC    (LSEQ/CL)        // 49 chunks
#define NBLK  (NC*3*BATCH)     // 588 scan blocks

typedef __attribute__((ext_vector_type(8))) short short8;
typedef __attribute__((ext_vector_type(4))) short short4v;
typedef __attribute__((ext_vector_type(4))) float floatx4;

__device__ __forceinline__ float siluf(float x)  { return x / (1.f + __expf(-x)); }
__device__ __forceinline__ float geluf(float x)  { return 0.5f * x * (1.f + erff(x * 0.70710678118654752f)); }
__device__ __forceinline__ float softplusf(float x) { return (x > 20.f) ? x : log1pf(__expf(x)); }
__device__ __forceinline__ float bf2f(short u) {
    union { unsigned int i; float f; } cv; cv.i = ((unsigned int)(unsigned short)u) << 16; return cv.f;
}
__device__ __forceinline__ short f2bf_bits(float v) {
    __hip_bfloat16 h = __float2bfloat16(v);
    return *(short*)&h;
}

// ---------------- weight prep: fp32->bf16 for 4 weights + combined W_comb[416,384] ----------------
#define WSZ0 147456  // in_proj_w 768*192
#define WSZ2 73728   // out_proj_w 192*384
#define WSZ3 147456  // mlp_w1 768*192
#define WSZ4 147456  // mlp_w2 192*768
#define WSZC (NXC*DIN)
__global__ __launch_bounds__(256) void prep_weights(const float* __restrict__ w0,
                                                    const float* __restrict__ w2, const float* __restrict__ w3,
                                                    const float* __restrict__ w4,
                                                    const float* __restrict__ xp_w, const float* __restrict__ dt_w,
                                                    __hip_bfloat16* __restrict__ o0,
                                                    __hip_bfloat16* __restrict__ o2, __hip_bfloat16* __restrict__ o3,
                                                    __hip_bfloat16* __restrict__ o4,
                                                    __hip_bfloat16* __restrict__ wcomb) {
    int i = blockIdx.x * 256 + threadIdx.x;
    if (i < WSZ0) { o0[i] = __float2bfloat16(w0[i]); return; } i -= WSZ0;
    if (i < WSZ2) { o2[i] = __float2bfloat16(w2[i]); return; } i -= WSZ2;
    if (i < WSZ3) { o3[i] = __float2bfloat16(w3[i]); return; } i -= WSZ3;
    if (i < WSZ4) { o4[i] = __float2bfloat16(w4[i]); return; } i -= WSZ4;
    if (i < WSZC) {
        int row = i / DIN, k = i % DIN;
        float v;
        if (row < DIN) {
            v = 0.f;
#pragma unroll
            for (int r = 0; r < DTR; r++) v += dt_w[row * DTR + r] * xp_w[r * DIN + k];
        } else {
            v = xp_w[(row - DIN + DTR) * DIN + k];
        }
        wcomb[i] = __float2bfloat16(v);
    }
}

// ---------------- LayerNorm over C, LDS-tiled, coalesced ----------------
__global__ __launch_bounds__(256) void ln_kernel(const float* __restrict__ x,
                                                 const float* __restrict__ g,
                                                 const float* __restrict__ bta,
                                                 __hip_bfloat16* __restrict__ out) {
    __shared__ float tile[CCH * 65];
    __shared__ float gs[CCH], bs[CCH];
    int t = threadIdx.x;
    int b = blockIdx.y, hw0 = blockIdx.x * 64;
    const float* xb = x + (size_t)b * CCH * LSEQ + hw0;
#pragma unroll 8
    for (int k = 0; k < 48; k++) {
        int idx = k * 256 + t;
        int c = idx >> 6, w = idx & 63;
        tile[c * 65 + w] = xb[(size_t)c * LSEQ + w];
    }
    if (t < CCH) { gs[t] = g[t]; bs[t] = bta[t]; }
    __syncthreads();
    int lane = t & 63, wave = t >> 6;
    int tk = lane & 15, p = lane >> 4;
    int tok = wave * 16 + tk;
    float s = 0.f, s2 = 0.f;
#pragma unroll 8
    for (int i = 0; i < 48; i++) {
        float v = tile[(p * 48 + i) * 65 + tok];
        s += v; s2 += v * v;
    }
    s += __shfl_xor(s, 16); s2 += __shfl_xor(s2, 16);
    s += __shfl_xor(s, 32); s2 += __shfl_xor(s2, 32);
    float mean = s * (1.f / CCH);
    float rstd = rsqrtf(s2 * (1.f / CCH) - mean * mean + 1e-5f);
    int j = lane >> 2, q = lane & 3;
    float mj = __shfl(mean, j);
    float rj = __shfl(rstd, j);
    int wtok = wave * 16 + j;
    __hip_bfloat16* op = out + (size_t)(b * LSEQ + hw0 + wtok) * CCH + q * 48;
#pragma unroll
    for (int kk = 0; kk < 6; kk++) {
        short8 pk;
#pragma unroll
        for (int e = 0; e < 8; e++) {
            int c = q * 48 + kk * 8 + e;
            float v = (tile[c * 65 + wtok] - mj) * rj * gs[c] + bs[c];
            pk[e] = f2bf_bits(v);
        }
        *(short8*)(op + kk * 8) = pk;
    }
}

// ---------------- bf16 MFMA GEMM, 64x64 tile, double-buffered ----------------
// EPI: 0 = bf16 store via LDS transpose, 2 = +bias+GELU bf16, 3 = +res NCHW f4,
//      4 = +bias+res NCHW f4, 5 = split softplus/aux
template<int EPI, typename OutT>
__global__ __launch_bounds__(256) void gemm_mfma(const __hip_bfloat16* __restrict__ A,
                                                 const __hip_bfloat16* __restrict__ W,
                                                 const float* __restrict__ bias,
                                                 const float* __restrict__ res,
                                                 OutT* __restrict__ Cout,
                                                 float* __restrict__ aux,
                                                 int N, int K) {
    __shared__ __align__(16) __hip_bfloat16 AsBs[2][2][64 * 40];
    int tid = threadIdx.x;
    int bm = blockIdx.y * 64, bn = blockIdx.x * 64;
    int wave = tid >> 6, lane = tid & 63;
    int wm = (wave >> 1) * 32, wn = (wave & 1) * 32;
    int lm = lane & 15, quad = lane >> 4;
    floatx4 acc[2][2] = {};
    int lrow = tid >> 2;
    int lcol = (tid & 3) * 8;
    const int nk = K >> 5;
    short8 zero8 = {0,0,0,0,0,0,0,0};
    short8 ra, rb;
    ra = *(const short8*)(A + (size_t)(bm + lrow) * K + lcol);
    {
        int n0 = bn + lrow;
        rb = (n0 < N) ? *(const short8*)(W + (size_t)n0 * K + lcol) : zero8;
    }
    *(short8*)&AsBs[0][0][lrow * 40 + lcol] = ra;
    *(short8*)&AsBs[0][1][lrow * 40 + lcol] = rb;
    __syncthreads();
    for (int kk = 0; kk < nk; kk++) {
        int cur = kk & 1;
        bool more = (kk + 1 < nk);
        if (more) {
            int k0 = (kk + 1) * 32;
            ra = *(const short8*)(A + (size_t)(bm + lrow) * K + k0 + lcol);
            int n0 = bn + lrow;
            rb = (n0 < N) ? *(const short8*)(W + (size_t)n0 * K + k0 + lcol) : zero8;
        }
        short8 a[2], b[2];
#pragma unroll
        for (int i = 0; i < 2; i++) a[i] = *(const short8*)&AsBs[cur][0][(wm + i * 16 + lm) * 40 + quad * 8];
#pragma unroll
        for (int j = 0; j < 2; j++) b[j] = *(const short8*)&AsBs[cur][1][(wn + j * 16 + lm) * 40 + quad * 8];
#pragma unroll
        for (int i = 0; i < 2; i++)
#pragma unroll
            for (int j = 0; j < 2; j++)
                acc[i][j] = __builtin_amdgcn_mfma_f32_16x16x32_bf16(a[i], b[j], acc[i][j], 0, 0, 0);
        if (more) {
            int nxt = cur ^ 1;
            *(short8*)&AsBs[nxt][0][lrow * 40 + lcol] = ra;
            *(short8*)&AsBs[nxt][1][lrow * 40 + lcol] = rb;
        }
        __syncthreads();
    }
    if constexpr (EPI == 3 || EPI == 4) {
#pragma unroll
        for (int j = 0; j < 2; j++) {
            int n = bn + wn + j * 16 + lm;
            if (n >= N) continue;
            float bv = (EPI == 4) ? bias[n] : 0.f;
#pragma unroll
            for (int i = 0; i < 2; i++) {
                int mrow = bm + wm + i * 16 + quad * 4;
                int bb = mrow / LSEQ;
                int l0 = mrow % LSEQ;
                size_t oidx = ((size_t)(bb * CCH + n)) * LSEQ + l0;
                float4 xr = *(const float4*)(res + oidx);
                float4 v;
                v.x = acc[i][j][0] + bv + xr.x;
                v.y = acc[i][j][1] + bv + xr.y;
                v.z = acc[i][j][2] + bv + xr.z;
                v.w = acc[i][j][3] + bv + xr.w;
                *(float4*)((float*)Cout + oidx) = v;
            }
        }
        return;
    } else {
        __hip_bfloat16* tb = (__hip_bfloat16*)&AsBs[0][0][0];
        bool has_tile = (EPI != 5) || (bn < DIN);
        if (has_tile) {
#pragma unroll
            for (int j = 0; j < 2; j++) {
                int n = bn + wn + j * 16 + lm;
                float bv = (EPI == 2 || EPI == 5) ? bias[n] : 0.f;
#pragma unroll
                for (int i = 0; i < 2; i++) {
#pragma unroll
                    for (int r = 0; r < 4; r++) {
                        float v = acc[i][j][r];
                        if (EPI == 2) v = geluf(v + bv);
                        if (EPI == 5) v = softplusf(v + bv);
                        tb[(wm + i * 16 + quad * 4 + r) * 72 + wn + j * 16 + lm] = __float2bfloat16(v);
                    }
                }
            }
        }
        __syncthreads();
        if (has_tile) {
            int ldc = (EPI == 5) ? DIN : N;
            __hip_bfloat16* cb = (__hip_bfloat16*)Cout;
#pragma unroll
            for (int pass = 0; pass < 2; pass++) {
                int idx = pass * 256 + tid;
                int row = idx >> 3, chunk = idx & 7;
                short8 v = *(const short8*)&tb[row * 72 + chunk * 8];
                *(short8*)(cb + (size_t)(bm + row) * ldc + bn + chunk * 8) = v;
            }
        }
        if constexpr (EPI == 5) {
            if (bn >= DIN) {
#pragma unroll
                for (int j = 0; j < 2; j++) {
                    int n = bn + wn + j * 16 + lm;
                    if (n >= N) continue;
                    int nb = n - DIN;
#pragma unroll
                    for (int i = 0; i < 2; i++) {
                        int mrow = bm + wm + i * 16 + quad * 4;
#pragma unroll
                        for (int r = 0; r < 4; r++)
                            aux[(size_t)(mrow + r) * 32 + nb] = acc[i][j][r];
                    }
                }
            }
        }
    }
}

// ---------------- causal depthwise conv1d (k=3) + SiLU, 4 d's/thread ----------------
__global__ __launch_bounds__(256) void conv1d_silu(const __hip_bfloat16* __restrict__ xz,
                                                   const float* __restrict__ w,
                                                   const float* __restrict__ bias,
                                                   __hip_bfloat16* __restrict__ out_bf) {
    int idx = blockIdx.x * 256 + threadIdx.x;
    if (idx >= NTOK * (DIN / 4)) return;
    int m = idx / (DIN / 4), d = (idx % (DIN / 4)) * 4;
    int l = m % LSEQ;
    short4v cur = *(const short4v*)&xz[(size_t)m * (2 * DIN) + d];
    short4v p1 = {0,0,0,0}, p2 = {0,0,0,0};
    if (l >= 1) p1 = *(const short4v*)&xz[(size_t)(m - 1) * (2 * DIN) + d];
    if (l >= 2) p2 = *(const short4v*)&xz[(size_t)(m - 2) * (2 * DIN) + d];
    float4 bv = *(const float4*)&bias[d];
    short4v obv;
#pragma unroll
    for (int jj = 0; jj < 4; jj++) {
        float w0 = w[(d + jj) * 3 + 0], w1 = w[(d + jj) * 3 + 1], w2 = w[(d + jj) * 3 + 2];
        float acc = ((const float*)&bv)[jj] + w2 * bf2f(cur[jj]) + w1 * bf2f(p1[jj]) + w0 * bf2f(p2[jj]);
        obv[jj] = f2bf_bits(siluf(acc));
    }
    *(short4v*)&out_bf[(size_t)m * DIN + d] = obv;
}

// ---------------- fused selective scan: phase1 + global barrier + phase2 + barrier + phase3 ----------------
// grid (NC=49, DIN/128=3, BATCH=4) = 588 blocks; __launch_bounds__(256,4) => >=4 blocks/CU
// guaranteed co-resident (capacity >= 1024 > 588), so the counter barrier cannot deadlock.
__device__ __forceinline__ void global_barrier(unsigned* cnt, unsigned target) {
    __syncthreads();
    if (threadIdx.x == 0) {
        __threadfence();
        atomicAdd(cnt, 1u);
        while (__hip_atomic_load(cnt, __ATOMIC_ACQUIRE, __HIP_MEMORY_SCOPE_AGENT) < target) {
            __builtin_amdgcn_s_sleep(8);
        }
    }
    __syncthreads();
}

__global__ __launch_bounds__(256, 4) void scan_fused(const __hip_bfloat16* __restrict__ delta,
                                                     const __hip_bfloat16* __restrict__ xm,
                                                     const float* __restrict__ bc,
                                                     const __hip_bfloat16* __restrict__ xz,
                                                     const float* __restrict__ A_log,
                                                     const float* __restrict__ Dskip,
                                                     float* __restrict__ Pbuf,
                                                     float* __restrict__ Qbuf,
                                                     float* __restrict__ Hin,
                                                     __hip_bfloat16* __restrict__ ybuf,
                                                     unsigned* __restrict__ bar) {
    __shared__ float bc_s[CL][32];    // 8 KB, persists across all 3 phases
    int t = threadIdx.x;
    int b = blockIdx.z, c = blockIdx.x, d0 = blockIdx.y * 128;
    int m0 = b * LSEQ + c * CL;
    {   // stage B|C once: CL x 32 floats = 2048; 256 thr x 8 floats
        int i = t >> 2, q = (t & 3) * 8;
        *(float4*)&bc_s[i][q]     = *(const float4*)&bc[(size_t)(m0 + i) * 32 + q];
        *(float4*)&bc_s[i][q + 4] = *(const float4*)&bc[(size_t)(m0 + i) * 32 + q + 4];
    }
    __syncthreads();
    int d = d0 + (t >> 1), half = t & 1;
    float An[8];
#pragma unroll
    for (int n4 = 0; n4 < 2; n4++) {
        float4 a = *(const float4*)&A_log[d * DST + half * 8 + n4 * 4];
        An[n4 * 4 + 0] = -__expf(a.x);
        An[n4 * 4 + 1] = -__expf(a.y);
        An[n4 * 4 + 2] = -__expf(a.z);
        An[n4 * 4 + 3] = -__expf(a.w);
    }
    // ---- phase 1: chunk transfer (P = exp(An*sum dlt), Q = local scan from 0) ----
    float Q[8];
#pragma unroll
    for (int n = 0; n < 8; n++) Q[n] = 0.f;
    float s = 0.f;
    const __hip_bfloat16* dp = delta + (size_t)m0 * DIN + d;
    const __hip_bfloat16* xp = xm    + (size_t)m0 * DIN + d;
#pragma unroll 4
    for (int i = 0; i < CL; i++) {
        float dlt = bf2f(*(const short*)(dp + (size_t)i * DIN));
        float xv  = bf2f(*(const short*)(xp + (size_t)i * DIN));
        s += dlt;
        float tt = dlt * xv;
#pragma unroll
        for (int n = 0; n < 8; n++) {
            float dA = __expf(dlt * An[n]);
            Q[n] = dA * Q[n] + tt * bc_s[i][half * 8 + n];
        }
    }
    size_t o = ((size_t)(b * NC + c) * DIN + d) * DST + half * 8;
#pragma unroll
    for (int n4 = 0; n4 < 2; n4++) {
        float4 Pv, Qv;
        Pv.x = __expf(An[n4 * 4 + 0] * s);
        Pv.y = __expf(An[n4 * 4 + 1] * s);
        Pv.z = __expf(An[n4 * 4 + 2] * s);
        Pv.w = __expf(An[n4 * 4 + 3] * s);
        Qv.x = Q[n4 * 4 + 0]; Qv.y = Q[n4 * 4 + 1];
        Qv.z = Q[n4 * 4 + 2]; Qv.w = Q[n4 * 4 + 3];
        *(float4*)&Pbuf[o + n4 * 4] = Pv;
        *(float4*)&Qbuf[o + n4 * 4] = Qv;
    }
    // ---- barrier 1 ----
    global_barrier(&bar[0], NBLK);
    // ---- phase 2: first 96 blocks chain over chunks ----
    {
        int fb = (blockIdx.z * gridDim.y + blockIdx.y) * gridDim.x + blockIdx.x;
        int gt = fb * 256 + t;
        if (gt < BATCH * DIN * DST) {
            int bb = gt / (DIN * DST);
            int rem = gt % (DIN * DST);
            float h = 0.f;
#pragma unroll 7
            for (int cc = 0; cc < NC; cc++) {
                size_t oo = (size_t)(bb * NC + cc) * (DIN * DST) + rem;
                Hin[oo] = h;
                h = Pbuf[oo] * h + Qbuf[oo];
            }
        }
    }
    // ---- barrier 2 ----
    global_barrier(&bar[1], NBLK);
    // ---- phase 3: re-scan from true h_in, emit gated y ----
    float h[8];
    {
        float4 h0 = *(const float4*)&Hin[o];
        float4 h1 = *(const float4*)&Hin[o + 4];
        h[0] = h0.x; h[1] = h0.y; h[2] = h0.z; h[3] = h0.w;
        h[4] = h1.x; h[5] = h1.y; h[6] = h1.z; h[7] = h1.w;
    }
    float Dv = Dskip[d];
    const __hip_bfloat16* zp = xz + (size_t)m0 * (2 * DIN) + DIN + d;
    __hip_bfloat16* yo = ybuf + (size_t)m0 * DIN + d;
#pragma unroll 2
    for (int i = 0; i < CL; i++) {
        float dlt = bf2f(*(const short*)(dp + (size_t)i * DIN));
        float xv  = bf2f(*(const short*)(xp + (size_t)i * DIN));
        float tt = dlt * xv;
        float y = 0.f;
#pragma unroll
        for (int n = 0; n < 8; n++) {
            float dA = __expf(dlt * An[n]);
            h[n] = dA * h[n] + tt * bc_s[i][half * 8 + n];
            y += h[n] * bc_s[i][16 + half * 8 + n];
        }
        y += __shfl_xor(y, 1);
        if (half == 0) {
            float zv = bf2f(*(const short*)(zp + (size_t)i * (2 * DIN)));
            yo[(size_t)i * DIN] = __float2bfloat16((y + xv * Dv) * siluf(zv));
        }
    }
}

// ---------------- depthwise 3x3 conv + BN + GELU + residual, 4 px/thread ----------------
__global__ __launch_bounds__(256) void dwconv_bn_gelu(const float* __restrict__ x1,
                                                      const float* __restrict__ wdw,
                                                      const float* __restrict__ bn_g,
                                                      const float* __restrict__ bn_b,
                                                      const float* __restrict__ bn_mean,
                                                      const float* __restrict__ bn_var,
                                                      float* __restrict__ x2) {
    int idx = blockIdx.x * 256 + threadIdx.x;
    if (idx >= NTOK * CCH / 4) return;
    int w4 = idx % (WW / 4); int tmp = idx / (WW / 4);
    int h = tmp % HH; tmp /= HH;
    int c = tmp % CCH; int b = tmp / CCH;
    int w0 = w4 * 4;
    const float* base = x1 + ((size_t)(b * CCH + c)) * LSEQ;
    float acc[4] = {0.f, 0.f, 0.f, 0.f};
    float4 mid0;
#pragma unroll
    for (int dh = -1; dh <= 1; dh++) {
        int hh = h + dh;
        if (hh < 0 || hh >= HH) { if (dh == 0) mid0 = *(const float4*)&base[h * WW + w0]; continue; }
        const float* row = base + hh * WW;
        float4 mid = *(const float4*)&row[w0];
        if (dh == 0) mid0 = mid;
        float lft = (w0 > 0) ? row[w0 - 1] : 0.f;
        float rgt = (w0 + 4 < WW) ? row[w0 + 4] : 0.f;
        float wA = wdw[c * 9 + (dh + 1) * 3 + 0];
        float wB = wdw[c * 9 + (dh + 1) * 3 + 1];
        float wC = wdw[c * 9 + (dh + 1) * 3 + 2];
        float in0 = lft, in1 = mid.x, in2 = mid.y, in3 = mid.z, in4 = mid.w, in5 = rgt;
        acc[0] += wA * in0 + wB * in1 + wC * in2;
        acc[1] += wA * in1 + wB * in2 + wC * in3;
        acc[2] += wA * in2 + wB * in3 + wC * in4;
        acc[3] += wA * in3 + wB * in4 + wC * in5;
    }
    float mu = bn_mean[c], rv = rsqrtf(bn_var[c] + 1e-5f) * bn_g[c], bb = bn_b[c];
    float4 o;
    o.x = mid0.x + geluf((acc[0] - mu) * rv + bb);
    o.y = mid0.y + geluf((acc[1] - mu) * rv + bb);
    o.z = mid0.z + geluf((acc[2] - mu) * rv + bb);
    o.w = mid0.w + geluf((acc[3] - mu) * rv + bb);
    *(float4*)&x2[((size_t)(b * CCH + c)) * LSEQ + h * WW + w0] = o;
}

extern "C" void kernel_launch(void* const* d_in, const int* in_sizes, int n_in,
                              void* d_out, int out_size, void* d_ws, size_t ws_size,
                              hipStream_t stream) {
    const float* x         = (const float*)d_in[0];
    const float* ln1_g     = (const float*)d_in[1];
    const float* ln1_b     = (const float*)d_in[2];
    const float* in_proj_w = (const float*)d_in[3];
    const float* conv_w    = (const float*)d_in[4];
    const float* conv_b    = (const float*)d_in[5];
    const float* x_proj_w  = (const float*)d_in[6];
    const float* dt_proj_w = (const float*)d_in[7];
    const float* dt_proj_b = (const float*)d_in[8];
    const float* A_log     = (const float*)d_in[9];
    const float* Dskip     = (const float*)d_in[10];
    const float* out_proj_w= (const float*)d_in[11];
    const float* dw_w      = (const float*)d_in[12];
    const float* bn_g      = (const float*)d_in[13];
    const float* bn_b      = (const float*)d_in[14];
    const float* bn_mean   = (const float*)d_in[15];
    const float* bn_var    = (const float*)d_in[16];
    const float* ln2_g     = (const float*)d_in[17];
    const float* ln2_b     = (const float*)d_in[18];
    const float* mlp_w1    = (const float*)d_in[19];
    const float* mlp_b1    = (const float*)d_in[20];
    const float* mlp_w2    = (const float*)d_in[21];
    const float* mlp_b2    = (const float*)d_in[22];
    float* out = (float*)d_out;

    // ---- workspace layout ----
    char* wsb = (char*)d_ws;
    __hip_bfloat16* xz_bf     = (__hip_bfloat16*)wsb;                 wsb += (size_t)NTOK * 768 * 2;
    __hip_bfloat16* xm_bf     = (__hip_bfloat16*)wsb;                 wsb += (size_t)NTOK * DIN * 2;
    __hip_bfloat16* delta_bf  = (__hip_bfloat16*)wsb;                 wsb += (size_t)NTOK * DIN * 2;
    float*          bc        = (float*)wsb;                          wsb += (size_t)NTOK * 32 * 4;
    float*          Pbuf      = (float*)wsb;                          wsb += (size_t)NTOK * 96 * 4;
    float*          Qbuf      = (float*)wsb;                          wsb += (size_t)NTOK * 96 * 4;
    float*          Hin       = (float*)wsb;                          wsb += (size_t)NTOK * 96 * 4;
    float*          x1        = (float*)wsb;                          wsb += (size_t)NTOK * CCH * 4;
    float*          x2        = (float*)wsb;                          wsb += (size_t)NTOK * CCH * 4;
    __hip_bfloat16* tokens_bf = (__hip_bfloat16*)wsb;                 wsb += (size_t)NTOK * CCH * 2;
    __hip_bfloat16* ybuf_bf   = (__hip_bfloat16*)wsb;                 wsb += (size_t)NTOK * DIN * 2;
    __hip_bfloat16* hidden_bf = (__hip_bfloat16*)wsb;                 wsb += (size_t)NTOK * 768 * 2;
    __hip_bfloat16* in_w_bf   = (__hip_bfloat16*)wsb;                 wsb += WSZ0 * 2;
    __hip_bfloat16* op_w_bf   = (__hip_bfloat16*)wsb;                 wsb += WSZ2 * 2;
    __hip_bfloat16* w1_bf     = (__hip_bfloat16*)wsb;                 wsb += WSZ3 * 2;
    __hip_bfloat16* w2_bf     = (__hip_bfloat16*)wsb;                 wsb += WSZ4 * 2;
    __hip_bfloat16* wcomb_bf  = (__hip_bfloat16*)wsb;                 wsb += (size_t)WSZC * 2;
    unsigned*       bar       = (unsigned*)wsb;                       wsb += 2 * sizeof(unsigned);

    // 0) zero barrier counters (graph-capturable), weight prep
    hipMemsetAsync(bar, 0, 2 * sizeof(unsigned), stream);
    prep_weights<<<(WSZ0 + WSZ2 + WSZ3 + WSZ4 + WSZC + 255) / 256, 256, 0, stream>>>(
        in_proj_w, out_proj_w, mlp_w1, mlp_w2, x_proj_w, dt_proj_w,
        in_w_bf, op_w_bf, w1_bf, w2_bf, wcomb_bf);
    // 1) LN1 -> tokens_bf
    ln_kernel<<<dim3(LSEQ / 64, BATCH), 256, 0, stream>>>(x, ln1_g, ln1_b, tokens_bf);
    // 2) in_proj (MFMA) -> xz bf16
    gemm_mfma<0, __hip_bfloat16><<<dim3(768 / 64, NTOK / 64), 256, 0, stream>>>(tokens_bf, in_w_bf, nullptr, nullptr, xz_bf, nullptr, 768, CCH);
    // 3) conv1d + silu -> xm_bf
    conv1d_silu<<<(NTOK * (DIN / 4) + 255) / 256, 256, 0, stream>>>(xz_bf, conv_w, conv_b, xm_bf);
    // 4) combined x_proj+dt_proj (MFMA, N=416) -> delta_bf + bc
    gemm_mfma<5, __hip_bfloat16><<<dim3(7, NTOK / 64), 256, 0, stream>>>(xm_bf, wcomb_bf, dt_proj_b, nullptr, delta_bf, bc, NXC, DIN);
    // 5) fused selective scan -> ybuf_bf
    scan_fused<<<dim3(NC, DIN / 128, BATCH), 256, 0, stream>>>(delta_bf, xm_bf, bc, xz_bf, A_log, Dskip, Pbuf, Qbuf, Hin, ybuf_bf, bar);
    // 6) out_proj (MFMA) fused residual-add + NCHW transpose store -> x1
    gemm_mfma<3, float><<<dim3(3, NTOK / 64), 256, 0, stream>>>(ybuf_bf, op_w_bf, nullptr, x, x1, nullptr, CCH, DIN);
    // 7) x2 = x1 + gelu(bn(dwconv3x3(x1)))
    dwconv_bn_gelu<<<(NTOK * CCH / 4 + 255) / 256, 256, 0, stream>>>(x1, dw_w, bn_g, bn_b, bn_mean, bn_var, x2);
    // 8) LN2 -> tokens_bf
    ln_kernel<<<dim3(LSEQ / 64, BATCH), 256, 0, stream>>>(x2, ln2_g, ln2_b, tokens_bf);
    // 9) mlp1 (MFMA) + bias + gelu -> hidden_bf
    gemm_mfma<2, __hip_bfloat16><<<dim3(768 / 64, NTOK / 64), 256, 0, stream>>>(tokens_bf, w1_bf, mlp_b1, nullptr, hidden_bf, nullptr, 768, CCH);
    // 10) mlp2 (MFMA) fused +b2 +x2 residual, NCHW store -> out
    gemm_mfma<4, float><<<dim3(3, NTOK / 64), 256, 0, stream>>>(hidden_bf, w2_bf, mlp_b2, x2, out, nullptr, CCH, 4 * CCH);
}

// Round 11
// 278.805 us; speedup vs baseline: 2.1418x; 2.1418x over previous
//
#include <hip/hip_runtime.h>
#include <hip/hip_bf16.h>
#include <math.h>

// ---- problem constants ----
#define BATCH 4
#define CCH   192
#define HH    56
#define WW    56
#define LSEQ  (HH*WW)          // 3136
#define NTOK  (BATCH*LSEQ)     // 12544
#define DST   16               // D_STATE
#define DIN   384              // D_INNER
#define DTR   12               // DT_RANK
#define NXC   416              // combined x_proj+dt_proj output cols
#define CL    32               // scan chunk length
#define NC    (LSEQ/CL)        // 98 chunks

typedef __attribute__((ext_vector_type(8))) short short8;
typedef __attribute__((ext_vector_type(4))) short short4v;
typedef __attribute__((ext_vector_type(4))) float floatx4;

__device__ __forceinline__ float siluf(float x)  { return x / (1.f + __expf(-x)); }
__device__ __forceinline__ float geluf(float x)  { return 0.5f * x * (1.f + erff(x * 0.70710678118654752f)); }
__device__ __forceinline__ float softplusf(float x) { return (x > 20.f) ? x : log1pf(__expf(x)); }
__device__ __forceinline__ float bf2f(short u) {
    union { unsigned int i; float f; } cv; cv.i = ((unsigned int)(unsigned short)u) << 16; return cv.f;
}
__device__ __forceinline__ short f2bf_bits(float v) {
    __hip_bfloat16 h = __float2bfloat16(v);
    return *(short*)&h;
}

// ---------------- weight prep: fp32->bf16 for 4 weights + combined W_comb[416,384] ----------------
#define WSZ0 147456  // in_proj_w 768*192
#define WSZ2 73728   // out_proj_w 192*384
#define WSZ3 147456  // mlp_w1 768*192
#define WSZ4 147456  // mlp_w2 192*768
#define WSZC (NXC*DIN)
__global__ __launch_bounds__(256) void prep_weights(const float* __restrict__ w0,
                                                    const float* __restrict__ w2, const float* __restrict__ w3,
                                                    const float* __restrict__ w4,
                                                    const float* __restrict__ xp_w, const float* __restrict__ dt_w,
                                                    __hip_bfloat16* __restrict__ o0,
                                                    __hip_bfloat16* __restrict__ o2, __hip_bfloat16* __restrict__ o3,
                                                    __hip_bfloat16* __restrict__ o4,
                                                    __hip_bfloat16* __restrict__ wcomb) {
    int i = blockIdx.x * 256 + threadIdx.x;
    if (i < WSZ0) { o0[i] = __float2bfloat16(w0[i]); return; } i -= WSZ0;
    if (i < WSZ2) { o2[i] = __float2bfloat16(w2[i]); return; } i -= WSZ2;
    if (i < WSZ3) { o3[i] = __float2bfloat16(w3[i]); return; } i -= WSZ3;
    if (i < WSZ4) { o4[i] = __float2bfloat16(w4[i]); return; } i -= WSZ4;
    if (i < WSZC) {
        int row = i / DIN, k = i % DIN;
        float v;
        if (row < DIN) {
            v = 0.f;
#pragma unroll
            for (int r = 0; r < DTR; r++) v += dt_w[row * DTR + r] * xp_w[r * DIN + k];
        } else {
            v = xp_w[(row - DIN + DTR) * DIN + k];
        }
        wcomb[i] = __float2bfloat16(v);
    }
}

// ---------------- LayerNorm over C, LDS-tiled, coalesced ----------------
__global__ __launch_bounds__(256) void ln_kernel(const float* __restrict__ x,
                                                 const float* __restrict__ g,
                                                 const float* __restrict__ bta,
                                                 __hip_bfloat16* __restrict__ out) {
    __shared__ float tile[CCH * 65];
    __shared__ float gs[CCH], bs[CCH];
    int t = threadIdx.x;
    int b = blockIdx.y, hw0 = blockIdx.x * 64;
    const float* xb = x + (size_t)b * CCH * LSEQ + hw0;
#pragma unroll 8
    for (int k = 0; k < 48; k++) {
        int idx = k * 256 + t;
        int c = idx >> 6, w = idx & 63;
        tile[c * 65 + w] = xb[(size_t)c * LSEQ + w];
    }
    if (t < CCH) { gs[t] = g[t]; bs[t] = bta[t]; }
    __syncthreads();
    int lane = t & 63, wave = t >> 6;
    int tk = lane & 15, p = lane >> 4;
    int tok = wave * 16 + tk;
    float s = 0.f, s2 = 0.f;
#pragma unroll 8
    for (int i = 0; i < 48; i++) {
        float v = tile[(p * 48 + i) * 65 + tok];
        s += v; s2 += v * v;
    }
    s += __shfl_xor(s, 16); s2 += __shfl_xor(s2, 16);
    s += __shfl_xor(s, 32); s2 += __shfl_xor(s2, 32);
    float mean = s * (1.f / CCH);
    float rstd = rsqrtf(s2 * (1.f / CCH) - mean * mean + 1e-5f);
    int j = lane >> 2, q = lane & 3;
    float mj = __shfl(mean, j);
    float rj = __shfl(rstd, j);
    int wtok = wave * 16 + j;
    __hip_bfloat16* op = out + (size_t)(b * LSEQ + hw0 + wtok) * CCH + q * 48;
#pragma unroll
    for (int kk = 0; kk < 6; kk++) {
        short8 pk;
#pragma unroll
        for (int e = 0; e < 8; e++) {
            int c = q * 48 + kk * 8 + e;
            float v = (tile[c * 65 + wtok] - mj) * rj * gs[c] + bs[c];
            pk[e] = f2bf_bits(v);
        }
        *(short8*)(op + kk * 8) = pk;
    }
}

// ---------------- bf16 MFMA GEMM, 64x64 tile, double-buffered ----------------
// grid: (row tiles = NTOK/64, col tiles) — row tiles fastest for W-tile sharing.
// EPI: 0 = bf16 store via LDS transpose, 2 = +bias+GELU bf16, 3 = +res NCHW f4,
//      4 = +bias+res NCHW f4, 5 = split softplus/aux
template<int EPI, typename OutT>
__global__ __launch_bounds__(256) void gemm_mfma(const __hip_bfloat16* __restrict__ A,
                                                 const __hip_bfloat16* __restrict__ W,
                                                 const float* __restrict__ bias,
                                                 const float* __restrict__ res,
                                                 OutT* __restrict__ Cout,
                                                 float* __restrict__ aux,
                                                 int N, int K) {
    __shared__ __align__(16) __hip_bfloat16 AsBs[2][2][64 * 40];
    int tid = threadIdx.x;
    int bm = blockIdx.x * 64, bn = blockIdx.y * 64;
    int wave = tid >> 6, lane = tid & 63;
    int wm = (wave >> 1) * 32, wn = (wave & 1) * 32;
    int lm = lane & 15, quad = lane >> 4;
    floatx4 acc[2][2] = {};
    int lrow = tid >> 2;
    int lcol = (tid & 3) * 8;
    const int nk = K >> 5;
    short8 zero8 = {0,0,0,0,0,0,0,0};
    short8 ra, rb;
    ra = *(const short8*)(A + (size_t)(bm + lrow) * K + lcol);
    {
        int n0 = bn + lrow;
        rb = (n0 < N) ? *(const short8*)(W + (size_t)n0 * K + lcol) : zero8;
    }
    *(short8*)&AsBs[0][0][lrow * 40 + lcol] = ra;
    *(short8*)&AsBs[0][1][lrow * 40 + lcol] = rb;
    __syncthreads();
    for (int kk = 0; kk < nk; kk++) {
        int cur = kk & 1;
        bool more = (kk + 1 < nk);
        if (more) {
            int k0 = (kk + 1) * 32;
            ra = *(const short8*)(A + (size_t)(bm + lrow) * K + k0 + lcol);
            int n0 = bn + lrow;
            rb = (n0 < N) ? *(const short8*)(W + (size_t)n0 * K + k0 + lcol) : zero8;
        }
        short8 a[2], b[2];
#pragma unroll
        for (int i = 0; i < 2; i++) a[i] = *(const short8*)&AsBs[cur][0][(wm + i * 16 + lm) * 40 + quad * 8];
#pragma unroll
        for (int j = 0; j < 2; j++) b[j] = *(const short8*)&AsBs[cur][1][(wn + j * 16 + lm) * 40 + quad * 8];
#pragma unroll
        for (int i = 0; i < 2; i++)
#pragma unroll
            for (int j = 0; j < 2; j++)
                acc[i][j] = __builtin_amdgcn_mfma_f32_16x16x32_bf16(a[i], b[j], acc[i][j], 0, 0, 0);
        if (more) {
            int nxt = cur ^ 1;
            *(short8*)&AsBs[nxt][0][lrow * 40 + lcol] = ra;
            *(short8*)&AsBs[nxt][1][lrow * 40 + lcol] = rb;
        }
        __syncthreads();
    }
    if constexpr (EPI == 3 || EPI == 4) {
#pragma unroll
        for (int j = 0; j < 2; j++) {
            int n = bn + wn + j * 16 + lm;
            if (n >= N) continue;
            float bv = (EPI == 4) ? bias[n] : 0.f;
#pragma unroll
            for (int i = 0; i < 2; i++) {
                int mrow = bm + wm + i * 16 + quad * 4;
                int bb = mrow / LSEQ;
                int l0 = mrow % LSEQ;
                size_t oidx = ((size_t)(bb * CCH + n)) * LSEQ + l0;
                float4 xr = *(const float4*)(res + oidx);
                float4 v;
                v.x = acc[i][j][0] + bv + xr.x;
                v.y = acc[i][j][1] + bv + xr.y;
                v.z = acc[i][j][2] + bv + xr.z;
                v.w = acc[i][j][3] + bv + xr.w;
                *(float4*)((float*)Cout + oidx) = v;
            }
        }
        return;
    } else {
        __hip_bfloat16* tb = (__hip_bfloat16*)&AsBs[0][0][0];
        bool has_tile = (EPI != 5) || (bn < DIN);
        if (has_tile) {
#pragma unroll
            for (int j = 0; j < 2; j++) {
                int n = bn + wn + j * 16 + lm;
                float bv = (EPI == 2 || EPI == 5) ? bias[n] : 0.f;
#pragma unroll
                for (int i = 0; i < 2; i++) {
#pragma unroll
                    for (int r = 0; r < 4; r++) {
                        float v = acc[i][j][r];
                        if (EPI == 2) v = geluf(v + bv);
                        if (EPI == 5) v = softplusf(v + bv);
                        tb[(wm + i * 16 + quad * 4 + r) * 72 + wn + j * 16 + lm] = __float2bfloat16(v);
                    }
                }
            }
        }
        __syncthreads();
        if (has_tile) {
            int ldc = (EPI == 5) ? DIN : N;
            __hip_bfloat16* cb = (__hip_bfloat16*)Cout;
#pragma unroll
            for (int pass = 0; pass < 2; pass++) {
                int idx = pass * 256 + tid;
                int row = idx >> 3, chunk = idx & 7;
                short8 v = *(const short8*)&tb[row * 72 + chunk * 8];
                *(short8*)(cb + (size_t)(bm + row) * ldc + bn + chunk * 8) = v;
            }
        }
        if constexpr (EPI == 5) {
            if (bn >= DIN) {
#pragma unroll
                for (int j = 0; j < 2; j++) {
                    int n = bn + wn + j * 16 + lm;
                    if (n >= N) continue;
                    int nb = n - DIN;
#pragma unroll
                    for (int i = 0; i < 2; i++) {
                        int mrow = bm + wm + i * 16 + quad * 4;
#pragma unroll
                        for (int r = 0; r < 4; r++)
                            aux[(size_t)(mrow + r) * 32 + nb] = acc[i][j][r];
                    }
                }
            }
        }
    }
}

// ---------------- causal depthwise conv1d (k=3) + SiLU, 4 d's/thread ----------------
__global__ __launch_bounds__(256) void conv1d_silu(const __hip_bfloat16* __restrict__ xz,
                                                   const float* __restrict__ w,
                                                   const float* __restrict__ bias,
                                                   __hip_bfloat16* __restrict__ out_bf) {
    int idx = blockIdx.x * 256 + threadIdx.x;
    if (idx >= NTOK * (DIN / 4)) return;
    int m = idx / (DIN / 4), d = (idx % (DIN / 4)) * 4;
    int l = m % LSEQ;
    short4v cur = *(const short4v*)&xz[(size_t)m * (2 * DIN) + d];
    short4v p1 = {0,0,0,0}, p2 = {0,0,0,0};
    if (l >= 1) p1 = *(const short4v*)&xz[(size_t)(m - 1) * (2 * DIN) + d];
    if (l >= 2) p2 = *(const short4v*)&xz[(size_t)(m - 2) * (2 * DIN) + d];
    float4 bv = *(const float4*)&bias[d];
    short4v obv;
#pragma unroll
    for (int jj = 0; jj < 4; jj++) {
        float w0 = w[(d + jj) * 3 + 0], w1 = w[(d + jj) * 3 + 1], w2 = w[(d + jj) * 3 + 2];
        float acc = ((const float*)&bv)[jj] + w2 * bf2f(cur[jj]) + w1 * bf2f(p1[jj]) + w0 * bf2f(p2[jj]);
        obv[jj] = f2bf_bits(siluf(acc));
    }
    *(short4v*)&out_bf[(size_t)m * DIN + d] = obv;
}

// ---------------- chunked selective scan, 2 threads/d (8 states each), bf16 inputs ----------------
__global__ __launch_bounds__(256) void scan_phase1(const __hip_bfloat16* __restrict__ delta,
                                                   const __hip_bfloat16* __restrict__ xm,
                                                   const float* __restrict__ bc,
                                                   const float* __restrict__ A_log,
                                                   float* __restrict__ Pbuf,
                                                   float* __restrict__ Qbuf) {
    __shared__ float b_s[CL][16];
    int t = threadIdx.x;
    int b = blockIdx.z, c = blockIdx.x, d0 = blockIdx.y * 128;
    int m0 = b * LSEQ + c * CL;
    {
        int i = t >> 3, q = (t & 7) * 2;
        *(float2*)&b_s[i][q] = *(const float2*)&bc[(size_t)(m0 + i) * 32 + q];
    }
    __syncthreads();
    int d = d0 + (t >> 1), half = t & 1;
    float An[8];
#pragma unroll
    for (int n4 = 0; n4 < 2; n4++) {
        float4 a = *(const float4*)&A_log[d * DST + half * 8 + n4 * 4];
        An[n4 * 4 + 0] = -__expf(a.x);
        An[n4 * 4 + 1] = -__expf(a.y);
        An[n4 * 4 + 2] = -__expf(a.z);
        An[n4 * 4 + 3] = -__expf(a.w);
    }
    float Q[8];
#pragma unroll
    for (int n = 0; n < 8; n++) Q[n] = 0.f;
    float s = 0.f;
    const __hip_bfloat16* dp = delta + (size_t)m0 * DIN + d;
    const __hip_bfloat16* xp = xm    + (size_t)m0 * DIN + d;
#pragma unroll 4
    for (int i = 0; i < CL; i++) {
        float dlt = bf2f(*(const short*)(dp + (size_t)i * DIN));
        float xv  = bf2f(*(const short*)(xp + (size_t)i * DIN));
        s += dlt;
        float tt = dlt * xv;
#pragma unroll
        for (int n = 0; n < 8; n++) {
            float dA = __expf(dlt * An[n]);
            Q[n] = dA * Q[n] + tt * b_s[i][half * 8 + n];
        }
    }
    size_t o = ((size_t)(b * NC + c) * DIN + d) * DST + half * 8;
#pragma unroll
    for (int n4 = 0; n4 < 2; n4++) {
        float4 Pv, Qv;
        Pv.x = __expf(An[n4 * 4 + 0] * s);
        Pv.y = __expf(An[n4 * 4 + 1] * s);
        Pv.z = __expf(An[n4 * 4 + 2] * s);
        Pv.w = __expf(An[n4 * 4 + 3] * s);
        Qv.x = Q[n4 * 4 + 0]; Qv.y = Q[n4 * 4 + 1];
        Qv.z = Q[n4 * 4 + 2]; Qv.w = Q[n4 * 4 + 3];
        *(float4*)&Pbuf[o + n4 * 4] = Pv;
        *(float4*)&Qbuf[o + n4 * 4] = Qv;
    }
}

__global__ __launch_bounds__(256) void scan_phase2(const float* __restrict__ Pbuf,
                                                   const float* __restrict__ Qbuf,
                                                   float* __restrict__ Hin) {
    int t = blockIdx.x * 256 + threadIdx.x;
    if (t >= BATCH * DIN * DST) return;
    int b = t / (DIN * DST);
    int rem = t % (DIN * DST);
    float h = 0.f;
#pragma unroll 7
    for (int c = 0; c < NC; c++) {
        size_t o = (size_t)(b * NC + c) * (DIN * DST) + rem;
        Hin[o] = h;
        h = Pbuf[o] * h + Qbuf[o];
    }
}

__global__ __launch_bounds__(256) void scan_phase3(const __hip_bfloat16* __restrict__ delta,
                                                   const __hip_bfloat16* __restrict__ xm,
                                                   const float* __restrict__ bc,
                                                   const __hip_bfloat16* __restrict__ xz,
                                                   const float* __restrict__ A_log,
                                                   const float* __restrict__ Dskip,
                                                   const float* __restrict__ Hin,
                                                   __hip_bfloat16* __restrict__ ybuf) {
    __shared__ float bc_s[CL][32];
    int t = threadIdx.x;
    int b = blockIdx.z, c = blockIdx.x, d0 = blockIdx.y * 128;
    int m0 = b * LSEQ + c * CL;
    {
        int i = t >> 3, q = (t & 7) * 4;
        *(float4*)&bc_s[i][q] = *(const float4*)&bc[(size_t)(m0 + i) * 32 + q];
    }
    __syncthreads();
    int d = d0 + (t >> 1), half = t & 1;
    float An[8];
#pragma unroll
    for (int n4 = 0; n4 < 2; n4++) {
        float4 a = *(const float4*)&A_log[d * DST + half * 8 + n4 * 4];
        An[n4 * 4 + 0] = -__expf(a.x);
        An[n4 * 4 + 1] = -__expf(a.y);
        An[n4 * 4 + 2] = -__expf(a.z);
        An[n4 * 4 + 3] = -__expf(a.w);
    }
    float h[8];
    size_t o = ((size_t)(b * NC + c) * DIN + d) * DST + half * 8;
    {
        float4 h0 = *(const float4*)&Hin[o];
        float4 h1 = *(const float4*)&Hin[o + 4];
        h[0] = h0.x; h[1] = h0.y; h[2] = h0.z; h[3] = h0.w;
        h[4] = h1.x; h[5] = h1.y; h[6] = h1.z; h[7] = h1.w;
    }
    float Dv = Dskip[d];
    const __hip_bfloat16* dp = delta + (size_t)m0 * DIN + d;
    const __hip_bfloat16* xp = xm    + (size_t)m0 * DIN + d;
    const __hip_bfloat16* zp = xz + (size_t)m0 * (2 * DIN) + DIN + d;
    __hip_bfloat16* yo = ybuf + (size_t)m0 * DIN + d;
#pragma unroll 2
    for (int i = 0; i < CL; i++) {
        float dlt = bf2f(*(const short*)(dp + (size_t)i * DIN));
        float xv  = bf2f(*(const short*)(xp + (size_t)i * DIN));
        float tt = dlt * xv;
        float y = 0.f;
#pragma unroll
        for (int n = 0; n < 8; n++) {
            float dA = __expf(dlt * An[n]);
            h[n] = dA * h[n] + tt * bc_s[i][half * 8 + n];
            y += h[n] * bc_s[i][16 + half * 8 + n];
        }
        y += __shfl_xor(y, 1);
        if (half == 0) {
            float zv = bf2f(*(const short*)(zp + (size_t)i * (2 * DIN)));
            yo[(size_t)i * DIN] = __float2bfloat16((y + xv * Dv) * siluf(zv));
        }
    }
}

// ---------------- depthwise 3x3 conv + BN + GELU + residual, 4 px/thread ----------------
__global__ __launch_bounds__(256) void dwconv_bn_gelu(const float* __restrict__ x1,
                                                      const float* __restrict__ wdw,
                                                      const float* __restrict__ bn_g,
                                                      const float* __restrict__ bn_b,
                                                      const float* __restrict__ bn_mean,
                                                      const float* __restrict__ bn_var,
                                                      float* __restrict__ x2) {
    int idx = blockIdx.x * 256 + threadIdx.x;
    if (idx >= NTOK * CCH / 4) return;
    int w4 = idx % (WW / 4); int tmp = idx / (WW / 4);
    int h = tmp % HH; tmp /= HH;
    int c = tmp % CCH; int b = tmp / CCH;
    int w0 = w4 * 4;
    const float* base = x1 + ((size_t)(b * CCH + c)) * LSEQ;
    float acc[4] = {0.f, 0.f, 0.f, 0.f};
    float4 mid0;
#pragma unroll
    for (int dh = -1; dh <= 1; dh++) {
        int hh = h + dh;
        if (hh < 0 || hh >= HH) { if (dh == 0) mid0 = *(const float4*)&base[h * WW + w0]; continue; }
        const float* row = base + hh * WW;
        float4 mid = *(const float4*)&row[w0];
        if (dh == 0) mid0 = mid;
        float lft = (w0 > 0) ? row[w0 - 1] : 0.f;
        float rgt = (w0 + 4 < WW) ? row[w0 + 4] : 0.f;
        float wA = wdw[c * 9 + (dh + 1) * 3 + 0];
        float wB = wdw[c * 9 + (dh + 1) * 3 + 1];
        float wC = wdw[c * 9 + (dh + 1) * 3 + 2];
        float in0 = lft, in1 = mid.x, in2 = mid.y, in3 = mid.z, in4 = mid.w, in5 = rgt;
        acc[0] += wA * in0 + wB * in1 + wC * in2;
        acc[1] += wA * in1 + wB * in2 + wC * in3;
        acc[2] += wA * in2 + wB * in3 + wC * in4;
        acc[3] += wA * in3 + wB * in4 + wC * in5;
    }
    float mu = bn_mean[c], rv = rsqrtf(bn_var[c] + 1e-5f) * bn_g[c], bb = bn_b[c];
    float4 o;
    o.x = mid0.x + geluf((acc[0] - mu) * rv + bb);
    o.y = mid0.y + geluf((acc[1] - mu) * rv + bb);
    o.z = mid0.z + geluf((acc[2] - mu) * rv + bb);
    o.w = mid0.w + geluf((acc[3] - mu) * rv + bb);
    *(float4*)&x2[((size_t)(b * CCH + c)) * LSEQ + h * WW + w0] = o;
}

extern "C" void kernel_launch(void* const* d_in, const int* in_sizes, int n_in,
                              void* d_out, int out_size, void* d_ws, size_t ws_size,
                              hipStream_t stream) {
    const float* x         = (const float*)d_in[0];
    const float* ln1_g     = (const float*)d_in[1];
    const float* ln1_b     = (const float*)d_in[2];
    const float* in_proj_w = (const float*)d_in[3];
    const float* conv_w    = (const float*)d_in[4];
    const float* conv_b    = (const float*)d_in[5];
    const float* x_proj_w  = (const float*)d_in[6];
    const float* dt_proj_w = (const float*)d_in[7];
    const float* dt_proj_b = (const float*)d_in[8];
    const float* A_log     = (const float*)d_in[9];
    const float* Dskip     = (const float*)d_in[10];
    const float* out_proj_w= (const float*)d_in[11];
    const float* dw_w      = (const float*)d_in[12];
    const float* bn_g      = (const float*)d_in[13];
    const float* bn_b      = (const float*)d_in[14];
    const float* bn_mean   = (const float*)d_in[15];
    const float* bn_var    = (const float*)d_in[16];
    const float* ln2_g     = (const float*)d_in[17];
    const float* ln2_b     = (const float*)d_in[18];
    const float* mlp_w1    = (const float*)d_in[19];
    const float* mlp_b1    = (const float*)d_in[20];
    const float* mlp_w2    = (const float*)d_in[21];
    const float* mlp_b2    = (const float*)d_in[22];
    float* out = (float*)d_out;

    // ---- workspace layout ----
    char* wsb = (char*)d_ws;
    __hip_bfloat16* xz_bf     = (__hip_bfloat16*)wsb;                 wsb += (size_t)NTOK * 768 * 2;
    __hip_bfloat16* xm_bf     = (__hip_bfloat16*)wsb;                 wsb += (size_t)NTOK * DIN * 2;
    __hip_bfloat16* delta_bf  = (__hip_bfloat16*)wsb;                 wsb += (size_t)NTOK * DIN * 2;
    float*          bc        = (float*)wsb;                          wsb += (size_t)NTOK * 32 * 4;
    float*          Pbuf      = (float*)wsb;                          wsb += (size_t)NTOK * 192 * 4;
    float*          Qbuf      = (float*)wsb;                          wsb += (size_t)NTOK * 192 * 4;
    float*          Hin       = (float*)wsb;                          wsb += (size_t)NTOK * 192 * 4;
    float*          x1        = (float*)wsb;                          wsb += (size_t)NTOK * CCH * 4;
    float*          x2        = (float*)wsb;                          wsb += (size_t)NTOK * CCH * 4;
    __hip_bfloat16* tokens_bf = (__hip_bfloat16*)wsb;                 wsb += (size_t)NTOK * CCH * 2;
    __hip_bfloat16* ybuf_bf   = (__hip_bfloat16*)wsb;                 wsb += (size_t)NTOK * DIN * 2;
    __hip_bfloat16* hidden_bf = (__hip_bfloat16*)wsb;                 wsb += (size_t)NTOK * 768 * 2;
    __hip_bfloat16* in_w_bf   = (__hip_bfloat16*)wsb;                 wsb += WSZ0 * 2;
    __hip_bfloat16* op_w_bf   = (__hip_bfloat16*)wsb;                 wsb += WSZ2 * 2;
    __hip_bfloat16* w1_bf     = (__hip_bfloat16*)wsb;                 wsb += WSZ3 * 2;
    __hip_bfloat16* w2_bf     = (__hip_bfloat16*)wsb;                 wsb += WSZ4 * 2;
    __hip_bfloat16* wcomb_bf  = (__hip_bfloat16*)wsb;                 wsb += (size_t)WSZC * 2;

    // 0) weight prep (4x cvt + combined x/dt weight, one kernel)
    prep_weights<<<(WSZ0 + WSZ2 + WSZ3 + WSZ4 + WSZC + 255) / 256, 256, 0, stream>>>(
        in_proj_w, out_proj_w, mlp_w1, mlp_w2, x_proj_w, dt_proj_w,
        in_w_bf, op_w_bf, w1_bf, w2_bf, wcomb_bf);
    // 1) LN1 -> tokens_bf
    ln_kernel<<<dim3(LSEQ / 64, BATCH), 256, 0, stream>>>(x, ln1_g, ln1_b, tokens_bf);
    // 2) in_proj (MFMA) -> xz bf16
    gemm_mfma<0, __hip_bfloat16><<<dim3(NTOK / 64, 768 / 64), 256, 0, stream>>>(tokens_bf, in_w_bf, nullptr, nullptr, xz_bf, nullptr, 768, CCH);
    // 3) conv1d + silu -> xm_bf
    conv1d_silu<<<(NTOK * (DIN / 4) + 255) / 256, 256, 0, stream>>>(xz_bf, conv_w, conv_b, xm_bf);
    // 4) combined x_proj+dt_proj (MFMA, N=416) -> delta_bf + bc
    gemm_mfma<5, __hip_bfloat16><<<dim3(NTOK / 64, 7), 256, 0, stream>>>(xm_bf, wcomb_bf, dt_proj_b, nullptr, delta_bf, bc, NXC, DIN);
    // 5) chunked selective scan -> ybuf_bf
    scan_phase1<<<dim3(NC, DIN / 128, BATCH), 256, 0, stream>>>(delta_bf, xm_bf, bc, A_log, Pbuf, Qbuf);
    scan_phase2<<<(BATCH * DIN * DST + 255) / 256, 256, 0, stream>>>(Pbuf, Qbuf, Hin);
    scan_phase3<<<dim3(NC, DIN / 128, BATCH), 256, 0, stream>>>(delta_bf, xm_bf, bc, xz_bf, A_log, Dskip, Hin, ybuf_bf);
    // 6) out_proj (MFMA) fused residual-add + NCHW transpose store -> x1
    gemm_mfma<3, float><<<dim3(NTOK / 64, 3), 256, 0, stream>>>(ybuf_bf, op_w_bf, nullptr, x, x1, nullptr, CCH, DIN);
    // 7) x2 = x1 + gelu(bn(dwconv3x3(x1)))
    dwconv_bn_gelu<<<(NTOK * CCH / 4 + 255) / 256, 256, 0, stream>>>(x1, dw_w, bn_g, bn_b, bn_mean, bn_var, x2);
    // 8) LN2 -> tokens_bf
    ln_kernel<<<dim3(LSEQ / 64, BATCH), 256, 0, stream>>>(x2, ln2_g, ln2_b, tokens_bf);
    // 9) mlp1 (MFMA) + bias + gelu -> hidden_bf
    gemm_mfma<2, __hip_bfloat16><<<dim3(NTOK / 64, 768 / 64), 256, 0, stream>>>(tokens_bf, w1_bf, mlp_b1, nullptr, hidden_bf, nullptr, 768, CCH);
    // 10) mlp2 (MFMA) fused +b2 +x2 residual, NCHW store -> out
    gemm_mfma<4, float><<<dim3(NTOK / 64, 3), 256, 0, stream>>>(hidden_bf, w2_bf, mlp_b2, x2, out, nullptr, CCH, 4 * CCH);
}